// Round 2
// baseline (136.429 us; speedup 1.0000x reference)
//
#include <hip/hip_runtime.h>
#include <hip/hip_bf16.h>
#include <stdint.h>

// ZoeDepth attractor head, R3b: SPLIT into two uniformly-bound kernels.
// (Resubmission of R3 after infra failure; exp2 builtin replaced with the
// round-0-verified __expf path as the only change.)
// Theory: the fused kernel was phase-lockstepped (all counters <42%) —
// streaming, MFMA, and attractor phases serialized grid-wide. Kernel 1
// (zoed_gemm) is pure x-streaming + MFMA, storing A=softplus(MLP(x)) fp32
// into the first 16 planes of the out2 region (scratch; overwritten by
// kernel 2 after an intra-block read barrier — px-disjoint across blocks,
// so no cross-block hazard). Kernel 2 (zoed_attr) is a pure streaming
// attractor: 512 thr x 1024 blocks = 32 waves/CU (100% occupancy), no LDS.

#define HW 16384
#define ALPHA 300.0f

typedef short bf16x8_t __attribute__((ext_vector_type(8)));
typedef float f32x4_t __attribute__((ext_vector_type(4)));
typedef unsigned int u32x4_t __attribute__((ext_vector_type(4)));

__device__ __forceinline__ unsigned short f2bf(float f) {
  unsigned int u = __builtin_bit_cast(unsigned int, f);
  u += 0x7fffu + ((u >> 16) & 1u);
  return (unsigned short)(u >> 16);
}
__device__ __forceinline__ unsigned int pack2(float a, float b) {
  return (unsigned int)f2bf(a) | ((unsigned int)f2bf(b) << 16);
}

// ---------------------------------------------------------------------------
// Prep: w1 (128x256) and w2 (16x128) fp32 -> bf16 blobs in frag layout,
// 16B granules XOR-swizzled by (row&3). w1: 8 chunks x 8192 B @0.
// w2: 4 chunks x 1024 B @byte 65536.  (unchanged, verified)
// ---------------------------------------------------------------------------
__global__ void zoed_prep(const float* __restrict__ w1,
                          const float* __restrict__ w2,
                          unsigned short* __restrict__ blob) {
  int i = blockIdx.x * 256 + threadIdx.x;  // 136*256 = 34816 = 32768 + 2048
  if (i < 32768) {
    int o = i >> 8, c = i & 255;
    float v = w1[i];
    int idx = (c >> 5) * 4096 + o * 32 + ((((c >> 3) & 3) ^ (o & 3)) << 3) + (c & 7);
    blob[idx] = f2bf(v);
  } else {
    int i2 = i - 32768;
    int a = i2 >> 7, o = i2 & 127;
    float v = w2[i2];
    int idx = 32768 + (o >> 5) * 512 + a * 32 + ((((o >> 3) & 3) ^ (a & 3)) << 3) + (o & 7);
    blob[idx] = f2bf(v);
  }
}

// ---------------------------------------------------------------------------
// Kernel 1: MLP head only. Grid: 1024 blocks (4 n * 256 px-tiles of 64),
// 256 thr. Identical staging/GEMM structure to the verified fused kernel;
// epilogue stores A (16 x 64px fp32) to out2 planes [n*64 .. n*64+16).
// LDS: x dbuf 8K, hid 16K overlay -> 16 KiB total.
// ---------------------------------------------------------------------------
__global__ __launch_bounds__(256, 4) void zoed_gemm(
    const float* __restrict__ x, const float* __restrict__ b1,
    const float* __restrict__ b2, const unsigned short* __restrict__ wblob,
    float* __restrict__ out) {
  __shared__ __align__(16) char smem[16384];
  char* hid = smem;

  const int t = threadIdx.x;
  const int lane = t & 63;
  const int l15 = lane & 15;
  const int quad = lane >> 4;
  const int wv = t >> 6;
  const int wm = wv & 1;   // o half (0..64 / 64..128)
  const int wn = wv >> 1;  // p half (0..32 / 32..64)
  const int sw = ((quad ^ (lane & 3)) << 4);

  const int blk = blockIdx.x;
  const int n = blk >> 8;
  const int p0 = (blk & 255) << 6;

  const int sp = t & 63;  // staging pixel row
  const int sg = t >> 6;  // staging channel granule 0..3

  // ---- pre-issue x chunks 0..3 (32 loads outstanding) ----
  const float* xsbase = x + (size_t)(n * 256 + sg * 8) * HW + p0 + sp;
  float xr[4][8];
#pragma unroll
  for (int c = 0; c < 4; c++)
#pragma unroll
    for (int j = 0; j < 8; j++)
      xr[c][j] = xsbase[(size_t)(c * 32 + j) * HW];

  // ---- pre-issue w1 frags for chunk 0 (direct from L2-hot blob) ----
  const char* wbase = (const char*)wblob + (wm * 64 + l15) * 64 + sw;
  bf16x8_t afn[4];
#pragma unroll
  for (int tm = 0; tm < 4; tm++)
    afn[tm] = *(const bf16x8_t*)(wbase + tm * 1024);

  f32x4_t acc[4][2];
#pragma unroll
  for (int i = 0; i < 4; i++)
#pragma unroll
    for (int j = 0; j < 2; j++) acc[i][j] = (f32x4_t){0.f, 0.f, 0.f, 0.f};

#pragma unroll
  for (int kb = 0; kb < 8; ++kb) {
    char* xb = smem + (kb & 1) * 4096;
    // current w1 frags; issue next chunk's
    bf16x8_t afc[4];
#pragma unroll
    for (int tm = 0; tm < 4; tm++) afc[tm] = afn[tm];
    if (kb < 7) {
#pragma unroll
      for (int tm = 0; tm < 4; tm++)
        afn[tm] = *(const bf16x8_t*)(wbase + (kb + 1) * 8192 + tm * 1024);
    }
    // pack chunk kb -> LDS dbuf
    {
      u32x4_t v = {pack2(xr[kb & 3][0], xr[kb & 3][1]),
                   pack2(xr[kb & 3][2], xr[kb & 3][3]),
                   pack2(xr[kb & 3][4], xr[kb & 3][5]),
                   pack2(xr[kb & 3][6], xr[kb & 3][7])};
      *(u32x4_t*)(xb + sp * 64 + ((sg ^ (sp & 3)) << 4)) = v;
    }
    // refill slot with chunk kb+4 (keeps 24-32 loads in flight)
    if (kb < 4) {
#pragma unroll
      for (int j = 0; j < 8; j++)
        xr[kb & 3][j] = xsbase[(size_t)((kb + 4) * 32 + j) * HW];
    }
    __syncthreads();
    // fragments + 8 MFMAs
    bf16x8_t bfm[2];
#pragma unroll
    for (int tn = 0; tn < 2; tn++)
      bfm[tn] = *(const bf16x8_t*)(xb + (wn * 32 + tn * 16 + l15) * 64 + sw);
#pragma unroll
    for (int tm = 0; tm < 4; tm++)
#pragma unroll
      for (int tn = 0; tn < 2; tn++)
        acc[tm][tn] = __builtin_amdgcn_mfma_f32_16x16x32_bf16(
            afc[tm], bfm[tn], acc[tm][tn], 0, 0, 0);
  }

  // ---- pre-issue w2 frags for GEMM2 ----
  bf16x8_t a2[4];
#pragma unroll
  for (int kc = 0; kc < 4; kc++)
    a2[kc] = *(const bf16x8_t*)((const char*)wblob + 65536 + kc * 1024 +
                                l15 * 64 + sw);

  __syncthreads();  // last frag reads done; hid overlay safe
  // ---- hidden epilogue: relu(acc + b1) -> bf16 -> hid chunks [p][o] ----
#pragma unroll
  for (int tm = 0; tm < 4; tm++) {
    f32x4_t b1v = *(const f32x4_t*)(b1 + wm * 64 + tm * 16 + quad * 4);
    int kc = wm * 2 + (tm >> 1);
    int g = (tm & 1) * 2 + (quad >> 1);
    int off8 = (quad & 1) * 8;
#pragma unroll
    for (int tn = 0; tn < 2; tn++) {
      f32x4_t h = acc[tm][tn] + b1v;
      h[0] = fmaxf(h[0], 0.f);
      h[1] = fmaxf(h[1], 0.f);
      h[2] = fmaxf(h[2], 0.f);
      h[3] = fmaxf(h[3], 0.f);
      int prow = wn * 32 + tn * 16 + l15;
      unsigned int* dst = (unsigned int*)(hid + kc * 4096 + prow * 64 +
                                          ((g ^ (prow & 3)) << 4) + off8);
      dst[0] = pack2(h[0], h[1]);
      dst[1] = pack2(h[2], h[3]);
    }
  }
  __syncthreads();
  // ---- GEMM2: A(16 x 64px) = softplus(w2 @ hidden + b2) -> global ----
  {
    f32x4_t acc2 = (f32x4_t){0.f, 0.f, 0.f, 0.f};
    const int prow = wv * 16 + l15;
#pragma unroll
    for (int kc = 0; kc < 4; kc++) {
      bf16x8_t bh = *(const bf16x8_t*)(hid + kc * 4096 + prow * 64 + sw);
      acc2 = __builtin_amdgcn_mfma_f32_16x16x32_bf16(a2[kc], bh, acc2, 0, 0, 0);
    }
    f32x4_t b2v = *(const f32x4_t*)(b2 + quad * 4);
    f32x4_t z = acc2 + b2v;
    // A[n][a][px] stored into out2 planes a = quad*4+r of image n
    float* Adst = out + (size_t)(256 + n * 64 + quad * 4) * HW + p0 + prow;
#pragma unroll
    for (int r = 0; r < 4; r++) {
      float zz = z[r];
      float spv = fmaxf(zz, 0.f) + log1pf(__expf(-fabsf(zz)));  // softplus
      Adst[(size_t)r * HW] = spv;  // regular store: keep L2-hot for kernel 2
    }
  }
}

// ---------------------------------------------------------------------------
// Kernel 2: attractor. Grid: 1024 blocks x 512 thr = 32 waves/CU (100% occ).
// Wave w <-> bin-group w (8 bins); lanes <-> 64 px (fully coalesced 256 B).
// Reads A from out2 planes [n*64 .. n*64+16), barrier (syncthreads drains
// vmcnt -> all A in regs), then overwrites those planes with real output.
// All 64 bins of a px live in this block => no cross-block read/write race.
// ---------------------------------------------------------------------------
__global__ __launch_bounds__(512, 8) void zoed_attr(
    const float* __restrict__ bprev, float* __restrict__ out) {
  const int t = threadIdx.x;
  const int px = t & 63;
  const int grp = t >> 6;  // 0..7: bin group of 8
  const int blk = blockIdx.x;
  const int n = blk >> 8;
  const int p0 = (blk & 255) << 6;

  // ---- load A[16] for this pixel (L1/L2-hot, 8x shared within block) ----
  const float* Abase = out + (size_t)(256 + n * 64) * HW + p0 + px;
  float Av[16];
#pragma unroll
  for (int a = 0; a < 16; a++) Av[a] = Abase[(size_t)a * HW];

  // ---- load 8 bin centers ----
  size_t obase = (size_t)(n * 64 + grp * 8) * HW + p0 + px;
  const float* bp = bprev + obase;
  float bpr[8];
#pragma unroll
  for (int b = 0; b < 8; b++) bpr[b] = bp[(size_t)b * HW];

  __syncthreads();  // drains vmcnt(0): every thread's A reads complete
                    // before any thread overwrites the A scratch planes

  float* o1 = out + obase;
  float* o2 = out + (size_t)256 * HW + obase;
#pragma unroll
  for (int b = 0; b < 8; b++) {
    float c = bpr[b];
    float d0 = 0.f, d1 = 0.f;
#pragma unroll
    for (int a = 0; a < 8; a++) {
      float dx = Av[a] - c;
      float e = __expf(dx * dx * -ALPHA);
      d0 = fmaf(e, dx, d0);
    }
#pragma unroll
    for (int a = 8; a < 16; a++) {
      float dx = Av[a] - c;
      float e = __expf(dx * dx * -ALPHA);
      d1 = fmaf(e, dx, d1);
    }
    float r = c + (d0 + d1);
    __builtin_nontemporal_store(r, o1 + (size_t)b * HW);
    __builtin_nontemporal_store(r, o2 + (size_t)b * HW);
  }
}

extern "C" void kernel_launch(void* const* d_in, const int* in_sizes, int n_in,
                              void* d_out, int out_size, void* d_ws,
                              size_t ws_size, hipStream_t stream) {
  const float* x = (const float*)d_in[0];      // 4*256*128*128
  const float* bprev = (const float*)d_in[1];  // 4*64*128*128
  const float* w1 = (const float*)d_in[2];     // 128*256
  const float* b1 = (const float*)d_in[3];     // 128
  const float* w2 = (const float*)d_in[4];     // 16*128
  const float* b2 = (const float*)d_in[5];     // 16
  float* outp = (float*)d_out;                 // 2 * 4194304
  unsigned short* blob = (unsigned short*)d_ws;  // 69632 B used

  zoed_prep<<<136, 256, 0, stream>>>(w1, w2, blob);
  zoed_gemm<<<1024, 256, 0, stream>>>(x, b1, b2, blob, outp);
  zoed_attr<<<1024, 512, 0, stream>>>(bprev, outp);
}